// Round 1
// baseline (3797.118 us; speedup 1.0000x reference)
//
#include <hip/hip_runtime.h>

#define D 256

typedef __attribute__((ext_vector_type(8))) short bf16x8;
typedef __attribute__((ext_vector_type(4))) float f32x4;

__device__ inline unsigned short f2bf(float f) {
  union { float f; unsigned u; } v; v.f = f;
  unsigned r = v.u + 0x7FFFu + ((v.u >> 16) & 1u);
  return (unsigned short)(r >> 16);
}

// Convert fp32 W[b][k][n] -> bf16 Wt[b][n][k]
__global__ void wprep_kernel(const float* __restrict__ w, unsigned short* __restrict__ wt,
                             int K, int total) {
  int idx = blockIdx.x * 256 + threadIdx.x;
  if (idx >= total) return;
  int k = idx % K;
  int rest = idx / K;
  int n = rest % D;
  int b = rest / D;
  float f = w[((size_t)b * K + k) * D + n];
  wt[idx] = f2bf(f);
}

__global__ void scatter_kernel(const float* __restrict__ ea, const int* __restrict__ dst,
                               float* __restrict__ agg, int E) {
  int idx = blockIdx.x * 256 + threadIdx.x;
  int e = idx >> 6;
  if (e >= E) return;
  int c = (idx & 63) * 4;
  float4 v = *(const float4*)(ea + (size_t)e * D + c);
  float* p = agg + (size_t)dst[e] * D + c;
  atomicAdd(p + 0, v.x);
  atomicAdd(p + 1, v.y);
  atomicAdd(p + 2, v.z);
  atomicAdd(p + 3, v.w);
}

// C[M,256] = act(A_eff @ W + bias). A_eff = concat of nChunk 256-wide chunks,
// each chunk either fp32 or bf16, with optional row-gather. Epilogue:
// ep==0: ReLU -> bf16 hout. ep==1: LayerNorm*g+b + residual add (fp32, in place).
__global__ __launch_bounds__(256) void mlp_gemm(
    const void* __restrict__ A0, const void* __restrict__ A1, const void* __restrict__ A2,
    const int* __restrict__ g0, const int* __restrict__ g1,
    int nChunk, const unsigned short* __restrict__ Wt, const float* __restrict__ bias,
    int M, int bf16mask, int ep,
    unsigned short* __restrict__ hout,
    const float* __restrict__ lng, const float* __restrict__ lnb,
    float* __restrict__ resid)
{
  __shared__ __align__(16) unsigned short As[64][40];   // 64 rows x 32 k (+8 pad)
  __shared__ __align__(16) unsigned short Bs[256][40];  // 256 n x 32 k (+8 pad)
  __shared__ float ps1[64][4];
  __shared__ float ps2[64][4];

  const int tid  = threadIdx.x;
  const int lane = tid & 63;
  const int wave = tid >> 6;
  const int lr   = lane & 15;
  const int lq   = lane >> 4;
  const int r0   = blockIdx.x * 64;
  const int K    = nChunk << 8;
  const int nkt  = nChunk << 3;

  // A staging role: row = tid>>2 (0..63), 8 k-elems at (tid&3)*8
  const int ra = tid >> 2;
  const int ka = (tid & 3) << 3;
  int rowA = r0 + ra;
  if (rowA > M - 1) rowA = M - 1;

  const int nb = tid >> 2;          // B staging: n rows nb, nb+64, nb+128, nb+192
  const int kb = (tid & 3) << 3;

  f32x4 acc[4][4];
  #pragma unroll
  for (int i = 0; i < 4; i++)
    #pragma unroll
    for (int j = 0; j < 4; j++)
      acc[i][j] = (f32x4){0.f, 0.f, 0.f, 0.f};

  for (int kt = 0; kt < nkt; ++kt) {
    const int chunk = kt >> 3;
    const int kloc  = (kt & 7) << 5;
    const void* Ap = (chunk == 0) ? A0 : (chunk == 1 ? A1 : A2);
    const int*  gp = (chunk == 0) ? g0 : (chunk == 1 ? g1 : (const int*)nullptr);
    int row = gp ? gp[rowA] : rowA;
    if ((bf16mask >> chunk) & 1) {
      const unsigned short* src = (const unsigned short*)Ap + (size_t)row * D + kloc + ka;
      *(uint4*)&As[ra][ka] = *(const uint4*)src;
    } else {
      const float* src = (const float*)Ap + (size_t)row * D + kloc + ka;
      float4 f0 = *(const float4*)src;
      float4 f1 = *(const float4*)(src + 4);
      uint4 p;
      p.x = f2bf(f0.x) | ((unsigned)f2bf(f0.y) << 16);
      p.y = f2bf(f0.z) | ((unsigned)f2bf(f0.w) << 16);
      p.z = f2bf(f1.x) | ((unsigned)f2bf(f1.y) << 16);
      p.w = f2bf(f1.z) | ((unsigned)f2bf(f1.w) << 16);
      *(uint4*)&As[ra][ka] = p;
    }
    const unsigned short* wsrc = Wt + (size_t)nb * K + (kt << 5) + kb;
    #pragma unroll
    for (int q = 0; q < 4; ++q) {
      *(uint4*)&Bs[nb + q * 64][kb] = *(const uint4*)(wsrc + (size_t)q * 64 * K);
    }
    __syncthreads();

    bf16x8 af[4], bq[4];
    #pragma unroll
    for (int mt = 0; mt < 4; ++mt)
      af[mt] = *(const bf16x8*)&As[mt * 16 + lr][lq * 8];
    #pragma unroll
    for (int nt = 0; nt < 4; ++nt)
      bq[nt] = *(const bf16x8*)&Bs[wave * 64 + nt * 16 + lr][lq * 8];
    #pragma unroll
    for (int mt = 0; mt < 4; ++mt)
      #pragma unroll
      for (int nt = 0; nt < 4; ++nt)
        acc[mt][nt] = __builtin_amdgcn_mfma_f32_16x16x32_bf16(af[mt], bq[nt], acc[mt][nt], 0, 0, 0);
    __syncthreads();
  }

  // bias
  #pragma unroll
  for (int nt = 0; nt < 4; ++nt) {
    const int col = wave * 64 + nt * 16 + lr;
    const float bv = bias[col];
    #pragma unroll
    for (int mt = 0; mt < 4; ++mt)
      #pragma unroll
      for (int r = 0; r < 4; ++r)
        acc[mt][nt][r] += bv;
  }

  if (ep == 0) {
    #pragma unroll
    for (int mt = 0; mt < 4; ++mt) {
      #pragma unroll
      for (int r = 0; r < 4; ++r) {
        int row = r0 + mt * 16 + lq * 4 + r;
        if (row < M) {
          #pragma unroll
          for (int nt = 0; nt < 4; ++nt) {
            int col = wave * 64 + nt * 16 + lr;
            float v = acc[mt][nt][r];
            v = v > 0.f ? v : 0.f;
            hout[(size_t)row * D + col] = f2bf(v);
          }
        }
      }
    }
  } else {
    #pragma unroll
    for (int mt = 0; mt < 4; ++mt) {
      #pragma unroll
      for (int r = 0; r < 4; ++r) {
        float s1 = 0.f, s2 = 0.f;
        #pragma unroll
        for (int nt = 0; nt < 4; ++nt) {
          float v = acc[mt][nt][r];
          s1 += v; s2 += v * v;
        }
        #pragma unroll
        for (int dlt = 1; dlt < 16; dlt <<= 1) {
          s1 += __shfl_xor(s1, dlt, 64);
          s2 += __shfl_xor(s2, dlt, 64);
        }
        if (lr == 0) {
          ps1[mt * 16 + lq * 4 + r][wave] = s1;
          ps2[mt * 16 + lq * 4 + r][wave] = s2;
        }
      }
    }
    __syncthreads();
    #pragma unroll
    for (int mt = 0; mt < 4; ++mt) {
      #pragma unroll
      for (int r = 0; r < 4; ++r) {
        int rl = mt * 16 + lq * 4 + r;
        int row = r0 + rl;
        float fs1 = ps1[rl][0] + ps1[rl][1] + ps1[rl][2] + ps1[rl][3];
        float fs2 = ps2[rl][0] + ps2[rl][1] + ps2[rl][2] + ps2[rl][3];
        float mean = fs1 * (1.f / 256.f);
        float var  = fs2 * (1.f / 256.f) - mean * mean;
        float rstd = rsqrtf(var + 1e-5f);
        if (row < M) {
          #pragma unroll
          for (int nt = 0; nt < 4; ++nt) {
            int col = wave * 64 + nt * 16 + lr;
            float v = (acc[mt][nt][r] - mean) * rstd * lng[col] + lnb[col];
            float* rp = resid + (size_t)row * D + col;
            *rp = *rp + v;
          }
        }
      }
    }
  }
}

extern "C" void kernel_launch(void* const* d_in, const int* in_sizes, int n_in,
                              void* d_out, int out_size, void* d_ws, size_t ws_size,
                              hipStream_t stream) {
  const float* x         = (const float*)d_in[0];
  const int*   eidx      = (const int*)d_in[1];
  const float* edge_attr = (const float*)d_in[2];
  const float* eW1 = (const float*)d_in[3];
  const float* eB1 = (const float*)d_in[4];
  const float* eW2 = (const float*)d_in[5];
  const float* eB2 = (const float*)d_in[6];
  const float* eW3 = (const float*)d_in[7];
  const float* eB3 = (const float*)d_in[8];
  const float* eLNg = (const float*)d_in[9];
  const float* eLNb = (const float*)d_in[10];
  const float* nW1 = (const float*)d_in[11];
  const float* nB1 = (const float*)d_in[12];
  const float* nW2 = (const float*)d_in[13];
  const float* nB2 = (const float*)d_in[14];
  const float* nW3 = (const float*)d_in[15];
  const float* nB3 = (const float*)d_in[16];
  const float* nLNg = (const float*)d_in[17];
  const float* nLNb = (const float*)d_in[18];

  const int Nn = in_sizes[0] / D;   // 10000
  const int E  = in_sizes[1] / 2;   // 60000
  const int B  = in_sizes[4] / D;   // 9

  const int* srcI = eidx;
  const int* dstI = eidx + E;

  char* wsp = (char*)d_ws;
  size_t off = 0;
  auto alloc = [&](size_t bytes) {
    char* p = wsp + off;
    off += (bytes + 255) & ~(size_t)255;
    return p;
  };
  unsigned short* eW1t = (unsigned short*)alloc((size_t)B * 768 * D * 2);
  unsigned short* eW2t = (unsigned short*)alloc((size_t)B * 256 * D * 2);
  unsigned short* eW3t = (unsigned short*)alloc((size_t)B * 256 * D * 2);
  unsigned short* nW1t = (unsigned short*)alloc((size_t)B * 512 * D * 2);
  unsigned short* nW2t = (unsigned short*)alloc((size_t)B * 256 * D * 2);
  unsigned short* nW3t = (unsigned short*)alloc((size_t)B * 256 * D * 2);
  float*          eabuf = (float*)alloc((size_t)E * D * 4);
  unsigned short* hbuf  = (unsigned short*)alloc((size_t)E * D * 2);
  float*          agg   = (float*)alloc((size_t)Nn * D * 4);

  float* xbuf = (float*)d_out;  // x state lives in d_out

  auto wp = [&](const float* w, unsigned short* wt, int K) {
    int total = B * K * D;
    wprep_kernel<<<(total + 255) / 256, 256, 0, stream>>>(w, wt, K, total);
  };
  wp(eW1, eW1t, 768);
  wp(eW2, eW2t, 256);
  wp(eW3, eW3t, 256);
  wp(nW1, nW1t, 512);
  wp(nW2, nW2t, 256);
  wp(nW3, nW3t, 256);

  hipMemcpyAsync(eabuf, edge_attr, (size_t)E * D * 4, hipMemcpyDeviceToDevice, stream);
  hipMemcpyAsync(xbuf, x, (size_t)Nn * D * 4, hipMemcpyDeviceToDevice, stream);

  const int gridE = (E + 63) / 64;
  const int gridN = (Nn + 63) / 64;

  for (int b = 0; b < B; ++b) {
    // edge MLP: h1 = relu([x[src],x[dst],ea] @ eW1 + eB1)
    mlp_gemm<<<gridE, 256, 0, stream>>>(xbuf, xbuf, eabuf, srcI, dstI, 3,
        eW1t + (size_t)b * 768 * D, eB1 + b * D, E, 0, 0, hbuf, nullptr, nullptr, nullptr);
    mlp_gemm<<<gridE, 256, 0, stream>>>(hbuf, nullptr, nullptr, nullptr, nullptr, 1,
        eW2t + (size_t)b * 256 * D, eB2 + b * D, E, 1, 0, hbuf, nullptr, nullptr, nullptr);
    mlp_gemm<<<gridE, 256, 0, stream>>>(hbuf, nullptr, nullptr, nullptr, nullptr, 1,
        eW3t + (size_t)b * 256 * D, eB3 + b * D, E, 1, 1, nullptr, eLNg + b * D, eLNb + b * D, eabuf);
    // agg = segment_sum(ea, dst)
    hipMemsetAsync(agg, 0, (size_t)Nn * D * 4, stream);
    scatter_kernel<<<(E * 64 + 255) / 256, 256, 0, stream>>>(eabuf, dstI, agg, E);
    // node MLP: x += LN([x, agg] @ ...)
    mlp_gemm<<<gridN, 256, 0, stream>>>(xbuf, agg, nullptr, nullptr, nullptr, 2,
        nW1t + (size_t)b * 512 * D, nB1 + b * D, Nn, 0, 0, hbuf, nullptr, nullptr, nullptr);
    mlp_gemm<<<gridN, 256, 0, stream>>>(hbuf, nullptr, nullptr, nullptr, nullptr, 1,
        nW2t + (size_t)b * 256 * D, nB2 + b * D, Nn, 1, 0, hbuf, nullptr, nullptr, nullptr);
    mlp_gemm<<<gridN, 256, 0, stream>>>(hbuf, nullptr, nullptr, nullptr, nullptr, 1,
        nW3t + (size_t)b * 256 * D, nB3 + b * D, Nn, 1, 1, nullptr, nLNg + b * D, nLNb + b * D, xbuf);
  }
}

// Round 2
// 2343.217 us; speedup vs baseline: 1.6205x; 1.6205x over previous
//
#include <hip/hip_runtime.h>

#define D 256

typedef __attribute__((ext_vector_type(8))) short bf16x8;
typedef __attribute__((ext_vector_type(4))) float f32x4;

__device__ inline unsigned short f2bf(float f) {
  union { float f; unsigned u; } v; v.f = f;
  unsigned r = v.u + 0x7FFFu + ((v.u >> 16) & 1u);
  return (unsigned short)(r >> 16);
}
__device__ inline float bf2f(unsigned short u) {
  union { unsigned u; float f; } v; v.u = ((unsigned)u) << 16;
  return v.f;
}

// Convert fp32 W[b][k][n] -> bf16 Wt[b][n][k]
__global__ void wprep_kernel(const float* __restrict__ w, unsigned short* __restrict__ wt,
                             int K, int total) {
  int idx = blockIdx.x * 256 + threadIdx.x;
  if (idx >= total) return;
  int k = idx % K;
  int rest = idx / K;
  int n = rest % D;
  int b = rest / D;
  float f = w[((size_t)b * K + k) * D + n];
  wt[idx] = f2bf(f);
}

// elementwise fp32 -> bf16, 4 at a time
__global__ void cvt_bf16_kernel(const float4* __restrict__ in, ushort4* __restrict__ out, int n4) {
  int i = blockIdx.x * 256 + threadIdx.x;
  if (i >= n4) return;
  float4 f = in[i];
  ushort4 o;
  o.x = f2bf(f.x); o.y = f2bf(f.y); o.z = f2bf(f.z); o.w = f2bf(f.w);
  out[i] = o;
}

// ---- CSR build ----
__global__ void hist_kernel(const int* __restrict__ dst, int* __restrict__ hist, int E) {
  int i = blockIdx.x * 256 + threadIdx.x;
  if (i < E) atomicAdd(&hist[dst[i]], 1);
}

__global__ void scan_kernel(const int* __restrict__ hist, int* __restrict__ offs, int Nn) {
  __shared__ int part[256];
  int t = threadIdx.x;
  int chunk = (Nn + 255) >> 8;
  int s = t * chunk;
  int e = s + chunk; if (e > Nn) e = Nn; if (s > Nn) s = Nn;
  int sum = 0;
  for (int i = s; i < e; ++i) sum += hist[i];
  part[t] = sum;
  __syncthreads();
  if (t == 0) {
    int run = 0;
    for (int i = 0; i < 256; ++i) { int v = part[i]; part[i] = run; run += v; }
  }
  __syncthreads();
  int run = part[t];
  for (int i = s; i < e; ++i) { offs[i] = run; run += hist[i]; }
  if (e == Nn) offs[Nn] = run;  // trailing threads write the same total
}

__global__ void fill_kernel(const int* __restrict__ dst, const int* __restrict__ offs,
                            int* __restrict__ cnt, int* __restrict__ eid, int E) {
  int i = blockIdx.x * 256 + threadIdx.x;
  if (i < E) {
    int d = dst[i];
    int p = offs[d] + atomicAdd(&cnt[d], 1);
    eid[p] = i;
  }
}

// agg[node] = sum over CSR bucket of eabf rows (bf16 in, fp32 out). One wave/node.
__global__ __launch_bounds__(256) void agg_kernel(
    const unsigned short* __restrict__ eabf, const int* __restrict__ eid,
    const int* __restrict__ offs, float* __restrict__ agg, int Nn) {
  int node = blockIdx.x * 4 + (threadIdx.x >> 6);
  if (node >= Nn) return;
  int lane = threadIdx.x & 63;
  int s = offs[node], e = offs[node + 1];
  float4 acc = make_float4(0.f, 0.f, 0.f, 0.f);
  for (int i = s; i < e; ++i) {
    int ed = eid[i];
    ushort4 v = *(const ushort4*)(eabf + (size_t)ed * D + lane * 4);
    acc.x += bf2f(v.x); acc.y += bf2f(v.y); acc.z += bf2f(v.z); acc.w += bf2f(v.w);
  }
  *(float4*)(agg + (size_t)node * D + lane * 4) = acc;
}

// C[M,256] = act(A_eff @ W + bias). A_eff = concat of nChunk 256-wide chunks,
// each chunk either fp32 or bf16, with optional row-gather. Epilogue:
// ep==0: ReLU -> bf16 hout. ep==1: LayerNorm*g+b + residual add (fp32, in place),
//        optional bf16 shadow write.
__global__ __launch_bounds__(256) void mlp_gemm(
    const void* __restrict__ A0, const void* __restrict__ A1, const void* __restrict__ A2,
    const int* __restrict__ g0, const int* __restrict__ g1,
    int nChunk, const unsigned short* __restrict__ Wt, const float* __restrict__ bias,
    int M, int bf16mask, int ep,
    unsigned short* __restrict__ hout,
    const float* __restrict__ lng, const float* __restrict__ lnb,
    float* __restrict__ resid, unsigned short* __restrict__ bfout)
{
  __shared__ __align__(16) unsigned short As[64][40];   // 64 rows x 32 k (+8 pad)
  __shared__ __align__(16) unsigned short Bs[256][40];  // 256 n x 32 k (+8 pad)
  __shared__ float ps1[64][4];
  __shared__ float ps2[64][4];

  const int tid  = threadIdx.x;
  const int lane = tid & 63;
  const int wave = tid >> 6;
  const int lr   = lane & 15;
  const int lq   = lane >> 4;
  const int r0   = blockIdx.x * 64;
  const int K    = nChunk << 8;
  const int nkt  = nChunk << 3;

  // A staging role: row = tid>>2 (0..63), 8 k-elems at (tid&3)*8
  const int ra = tid >> 2;
  const int ka = (tid & 3) << 3;
  int rowA = r0 + ra;
  if (rowA > M - 1) rowA = M - 1;

  const int nb = tid >> 2;          // B staging: n rows nb, nb+64, nb+128, nb+192
  const int kb = (tid & 3) << 3;

  f32x4 acc[4][4];
  #pragma unroll
  for (int i = 0; i < 4; i++)
    #pragma unroll
    for (int j = 0; j < 4; j++)
      acc[i][j] = (f32x4){0.f, 0.f, 0.f, 0.f};

  for (int kt = 0; kt < nkt; ++kt) {
    const int chunk = kt >> 3;
    const int kloc  = (kt & 7) << 5;
    const void* Ap = (chunk == 0) ? A0 : (chunk == 1 ? A1 : A2);
    const int*  gp = (chunk == 0) ? g0 : (chunk == 1 ? g1 : (const int*)nullptr);
    int row = gp ? gp[rowA] : rowA;
    if ((bf16mask >> chunk) & 1) {
      const unsigned short* src = (const unsigned short*)Ap + (size_t)row * D + kloc + ka;
      *(uint4*)&As[ra][ka] = *(const uint4*)src;
    } else {
      const float* src = (const float*)Ap + (size_t)row * D + kloc + ka;
      float4 f0 = *(const float4*)src;
      float4 f1 = *(const float4*)(src + 4);
      uint4 p;
      p.x = f2bf(f0.x) | ((unsigned)f2bf(f0.y) << 16);
      p.y = f2bf(f0.z) | ((unsigned)f2bf(f0.w) << 16);
      p.z = f2bf(f1.x) | ((unsigned)f2bf(f1.y) << 16);
      p.w = f2bf(f1.z) | ((unsigned)f2bf(f1.w) << 16);
      *(uint4*)&As[ra][ka] = p;
    }
    const unsigned short* wsrc = Wt + (size_t)nb * K + (kt << 5) + kb;
    #pragma unroll
    for (int q = 0; q < 4; ++q) {
      *(uint4*)&Bs[nb + q * 64][kb] = *(const uint4*)(wsrc + (size_t)q * 64 * K);
    }
    __syncthreads();

    bf16x8 af[4], bq[4];
    #pragma unroll
    for (int mt = 0; mt < 4; ++mt)
      af[mt] = *(const bf16x8*)&As[mt * 16 + lr][lq * 8];
    #pragma unroll
    for (int nt = 0; nt < 4; ++nt)
      bq[nt] = *(const bf16x8*)&Bs[wave * 64 + nt * 16 + lr][lq * 8];
    #pragma unroll
    for (int mt = 0; mt < 4; ++mt)
      #pragma unroll
      for (int nt = 0; nt < 4; ++nt)
        acc[mt][nt] = __builtin_amdgcn_mfma_f32_16x16x32_bf16(af[mt], bq[nt], acc[mt][nt], 0, 0, 0);
    __syncthreads();
  }

  // bias
  #pragma unroll
  for (int nt = 0; nt < 4; ++nt) {
    const int col = wave * 64 + nt * 16 + lr;
    const float bv = bias[col];
    #pragma unroll
    for (int mt = 0; mt < 4; ++mt)
      #pragma unroll
      for (int r = 0; r < 4; ++r)
        acc[mt][nt][r] += bv;
  }

  if (ep == 0) {
    #pragma unroll
    for (int mt = 0; mt < 4; ++mt) {
      #pragma unroll
      for (int r = 0; r < 4; ++r) {
        int row = r0 + mt * 16 + lq * 4 + r;
        if (row < M) {
          #pragma unroll
          for (int nt = 0; nt < 4; ++nt) {
            int col = wave * 64 + nt * 16 + lr;
            float v = acc[mt][nt][r];
            v = v > 0.f ? v : 0.f;
            hout[(size_t)row * D + col] = f2bf(v);
          }
        }
      }
    }
  } else {
    #pragma unroll
    for (int mt = 0; mt < 4; ++mt) {
      #pragma unroll
      for (int r = 0; r < 4; ++r) {
        float s1 = 0.f, s2 = 0.f;
        #pragma unroll
        for (int nt = 0; nt < 4; ++nt) {
          float v = acc[mt][nt][r];
          s1 += v; s2 += v * v;
        }
        #pragma unroll
        for (int dlt = 1; dlt < 16; dlt <<= 1) {
          s1 += __shfl_xor(s1, dlt, 64);
          s2 += __shfl_xor(s2, dlt, 64);
        }
        if (lr == 0) {
          ps1[mt * 16 + lq * 4 + r][wave] = s1;
          ps2[mt * 16 + lq * 4 + r][wave] = s2;
        }
      }
    }
    __syncthreads();
    #pragma unroll
    for (int mt = 0; mt < 4; ++mt) {
      #pragma unroll
      for (int r = 0; r < 4; ++r) {
        int rl = mt * 16 + lq * 4 + r;
        int row = r0 + rl;
        float fs1 = ps1[rl][0] + ps1[rl][1] + ps1[rl][2] + ps1[rl][3];
        float fs2 = ps2[rl][0] + ps2[rl][1] + ps2[rl][2] + ps2[rl][3];
        float mean = fs1 * (1.f / 256.f);
        float var  = fs2 * (1.f / 256.f) - mean * mean;
        float rstd = rsqrtf(var + 1e-5f);
        if (row < M) {
          #pragma unroll
          for (int nt = 0; nt < 4; ++nt) {
            int col = wave * 64 + nt * 16 + lr;
            float v = (acc[mt][nt][r] - mean) * rstd * lng[col] + lnb[col];
            float* rp = resid + (size_t)row * D + col;
            float nv = *rp + v;
            *rp = nv;
            if (bfout) bfout[(size_t)row * D + col] = f2bf(nv);
          }
        }
      }
    }
  }
}

extern "C" void kernel_launch(void* const* d_in, const int* in_sizes, int n_in,
                              void* d_out, int out_size, void* d_ws, size_t ws_size,
                              hipStream_t stream) {
  const float* x         = (const float*)d_in[0];
  const int*   eidx      = (const int*)d_in[1];
  const float* edge_attr = (const float*)d_in[2];
  const float* eW1 = (const float*)d_in[3];
  const float* eB1 = (const float*)d_in[4];
  const float* eW2 = (const float*)d_in[5];
  const float* eB2 = (const float*)d_in[6];
  const float* eW3 = (const float*)d_in[7];
  const float* eB3 = (const float*)d_in[8];
  const float* eLNg = (const float*)d_in[9];
  const float* eLNb = (const float*)d_in[10];
  const float* nW1 = (const float*)d_in[11];
  const float* nB1 = (const float*)d_in[12];
  const float* nW2 = (const float*)d_in[13];
  const float* nB2 = (const float*)d_in[14];
  const float* nW3 = (const float*)d_in[15];
  const float* nB3 = (const float*)d_in[16];
  const float* nLNg = (const float*)d_in[17];
  const float* nLNb = (const float*)d_in[18];

  const int Nn = in_sizes[0] / D;   // 10000
  const int E  = in_sizes[1] / 2;   // 60000
  const int B  = in_sizes[4] / D;   // 9

  const int* srcI = eidx;
  const int* dstI = eidx + E;

  char* wsp = (char*)d_ws;
  size_t off = 0;
  auto alloc = [&](size_t bytes) {
    char* p = wsp + off;
    off += (bytes + 255) & ~(size_t)255;
    return p;
  };
  unsigned short* eW1t = (unsigned short*)alloc((size_t)B * 768 * D * 2);
  unsigned short* eW2t = (unsigned short*)alloc((size_t)B * 256 * D * 2);
  unsigned short* eW3t = (unsigned short*)alloc((size_t)B * 256 * D * 2);
  unsigned short* nW1t = (unsigned short*)alloc((size_t)B * 512 * D * 2);
  unsigned short* nW2t = (unsigned short*)alloc((size_t)B * 256 * D * 2);
  unsigned short* nW3t = (unsigned short*)alloc((size_t)B * 256 * D * 2);
  float*          eabuf = (float*)alloc((size_t)E * D * 4);
  unsigned short* eabf  = (unsigned short*)alloc((size_t)E * D * 2);
  unsigned short* hbuf  = (unsigned short*)alloc((size_t)E * D * 2);
  float*          agg   = (float*)alloc((size_t)Nn * D * 4);
  int*            hist  = (int*)alloc((size_t)(Nn + 1) * 4);
  int*            offs  = (int*)alloc((size_t)(Nn + 1) * 4);
  int*            cnt   = (int*)alloc((size_t)Nn * 4);
  int*            eid   = (int*)alloc((size_t)E * 4);

  float* xbuf = (float*)d_out;  // x state lives in d_out

  auto wp = [&](const float* w, unsigned short* wt, int K) {
    int total = B * K * D;
    wprep_kernel<<<(total + 255) / 256, 256, 0, stream>>>(w, wt, K, total);
  };
  wp(eW1, eW1t, 768);
  wp(eW2, eW2t, 256);
  wp(eW3, eW3t, 256);
  wp(nW1, nW1t, 512);
  wp(nW2, nW2t, 256);
  wp(nW3, nW3t, 256);

  hipMemcpyAsync(eabuf, edge_attr, (size_t)E * D * 4, hipMemcpyDeviceToDevice, stream);
  hipMemcpyAsync(xbuf, x, (size_t)Nn * D * 4, hipMemcpyDeviceToDevice, stream);
  {
    int n4 = E * D / 4;
    cvt_bf16_kernel<<<(n4 + 255) / 256, 256, 0, stream>>>(
        (const float4*)edge_attr, (ushort4*)eabf, n4);
  }

  // CSR build (edge_index constant across blocks -> once per launch)
  hipMemsetAsync(hist, 0, (size_t)Nn * 4, stream);
  hipMemsetAsync(cnt, 0, (size_t)Nn * 4, stream);
  hist_kernel<<<(E + 255) / 256, 256, 0, stream>>>(dstI, hist, E);
  scan_kernel<<<1, 256, 0, stream>>>(hist, offs, Nn);
  fill_kernel<<<(E + 255) / 256, 256, 0, stream>>>(dstI, offs, cnt, eid, E);

  const int gridE = (E + 63) / 64;
  const int gridN = (Nn + 63) / 64;
  const int gridA = (Nn + 3) / 4;

  for (int b = 0; b < B; ++b) {
    // edge MLP: h1 = relu([x[src],x[dst],ea] @ eW1 + eB1)
    mlp_gemm<<<gridE, 256, 0, stream>>>(xbuf, xbuf, eabf, srcI, dstI, 3,
        eW1t + (size_t)b * 768 * D, eB1 + b * D, E, 4, 0, hbuf, nullptr, nullptr, nullptr, nullptr);
    mlp_gemm<<<gridE, 256, 0, stream>>>(hbuf, nullptr, nullptr, nullptr, nullptr, 1,
        eW2t + (size_t)b * 256 * D, eB2 + b * D, E, 1, 0, hbuf, nullptr, nullptr, nullptr, nullptr);
    mlp_gemm<<<gridE, 256, 0, stream>>>(hbuf, nullptr, nullptr, nullptr, nullptr, 1,
        eW3t + (size_t)b * 256 * D, eB3 + b * D, E, 1, 1, nullptr, eLNg + b * D, eLNb + b * D, eabuf, eabf);
    // agg = segment_sum(ea, dst) via CSR gather (deterministic, no atomics)
    agg_kernel<<<gridA, 256, 0, stream>>>(eabf, eid, offs, agg, Nn);
    // node MLP: x += LN([x, agg] @ ...)
    mlp_gemm<<<gridN, 256, 0, stream>>>(xbuf, agg, nullptr, nullptr, nullptr, 2,
        nW1t + (size_t)b * 512 * D, nB1 + b * D, Nn, 0, 0, hbuf, nullptr, nullptr, nullptr, nullptr);
    mlp_gemm<<<gridN, 256, 0, stream>>>(hbuf, nullptr, nullptr, nullptr, nullptr, 1,
        nW2t + (size_t)b * 256 * D, nB2 + b * D, Nn, 1, 0, hbuf, nullptr, nullptr, nullptr, nullptr);
    mlp_gemm<<<gridN, 256, 0, stream>>>(hbuf, nullptr, nullptr, nullptr, nullptr, 1,
        nW3t + (size_t)b * 256 * D, nB3 + b * D, Nn, 1, 1, nullptr, nLNg + b * D, nLNb + b * D, xbuf, nullptr);
  }
}

// Round 3
// 1788.690 us; speedup vs baseline: 2.1228x; 1.3100x over previous
//
#include <hip/hip_runtime.h>

#define D 256

typedef __attribute__((ext_vector_type(8))) short bf16x8;
typedef __attribute__((ext_vector_type(4))) float f32x4;

__device__ inline unsigned short f2bf(float f) {
  union { float f; unsigned u; } v; v.f = f;
  unsigned r = v.u + 0x7FFFu + ((v.u >> 16) & 1u);
  return (unsigned short)(r >> 16);
}
__device__ inline float bf2f(unsigned short u) {
  union { unsigned u; float f; } v; v.u = ((unsigned)u) << 16;
  return v.f;
}

// async global->LDS, 16B per lane. ldst must be wave-uniform; data lands at
// ldst + lane*16. gsrc is per-lane.
__device__ inline void gl_lds16(const void* gsrc, void* ldst) {
  __builtin_amdgcn_global_load_lds(
      (const __attribute__((address_space(1))) void*)gsrc,
      (__attribute__((address_space(3))) void*)ldst, 16, 0, 0);
}

// Convert fp32 W[b][k][n] -> bf16 Wt[b][n][k]
__global__ void wprep_kernel(const float* __restrict__ w, unsigned short* __restrict__ wt,
                             int K, int total) {
  int idx = blockIdx.x * 256 + threadIdx.x;
  if (idx >= total) return;
  int k = idx % K;
  int rest = idx / K;
  int n = rest % D;
  int b = rest / D;
  float f = w[((size_t)b * K + k) * D + n];
  wt[idx] = f2bf(f);
}

__global__ void cvt_bf16_kernel(const float4* __restrict__ in, ushort4* __restrict__ out, int n4) {
  int i = blockIdx.x * 256 + threadIdx.x;
  if (i >= n4) return;
  float4 f = in[i];
  ushort4 o;
  o.x = f2bf(f.x); o.y = f2bf(f.y); o.z = f2bf(f.z); o.w = f2bf(f.w);
  out[i] = o;
}

// ---- CSR build ----
__global__ void hist_kernel(const int* __restrict__ dst, int* __restrict__ hist, int E) {
  int i = blockIdx.x * 256 + threadIdx.x;
  if (i < E) atomicAdd(&hist[dst[i]], 1);
}

__global__ void scan_kernel(const int* __restrict__ hist, int* __restrict__ offs, int Nn) {
  __shared__ int part[256];
  int t = threadIdx.x;
  int chunk = (Nn + 255) >> 8;
  int s = t * chunk;
  int e = s + chunk; if (e > Nn) e = Nn; if (s > Nn) s = Nn;
  int sum = 0;
  for (int i = s; i < e; ++i) sum += hist[i];
  part[t] = sum;
  __syncthreads();
  if (t == 0) {
    int run = 0;
    for (int i = 0; i < 256; ++i) { int v = part[i]; part[i] = run; run += v; }
  }
  __syncthreads();
  int run = part[t];
  for (int i = s; i < e; ++i) { offs[i] = run; run += hist[i]; }
  if (e == Nn) offs[Nn] = run;
}

__global__ void fill_kernel(const int* __restrict__ dst, const int* __restrict__ offs,
                            int* __restrict__ cnt, int* __restrict__ eid, int E) {
  int i = blockIdx.x * 256 + threadIdx.x;
  if (i < E) {
    int d = dst[i];
    int p = offs[d] + atomicAdd(&cnt[d], 1);
    eid[p] = i;
  }
}

// agg[node] = sum over CSR bucket of eabf rows (bf16 in, fp32 out). One wave/node.
__global__ __launch_bounds__(256) void agg_kernel(
    const unsigned short* __restrict__ eabf, const int* __restrict__ eid,
    const int* __restrict__ offs, float* __restrict__ agg, int Nn) {
  int node = blockIdx.x * 4 + (threadIdx.x >> 6);
  if (node >= Nn) return;
  int lane = threadIdx.x & 63;
  int s = offs[node], e = offs[node + 1];
  float4 acc = make_float4(0.f, 0.f, 0.f, 0.f);
  for (int i = s; i < e; ++i) {
    int ed = eid[i];
    ushort4 v = *(const ushort4*)(eabf + (size_t)ed * D + lane * 4);
    acc.x += bf2f(v.x); acc.y += bf2f(v.y); acc.z += bf2f(v.z); acc.w += bf2f(v.w);
  }
  *(float4*)(agg + (size_t)node * D + lane * 4) = acc;
}

// Fused 3-layer MLP: out_resid += LN(relu(relu(A@W1+b1)@W2+b2)@W3+b3)*g+b
// A = concat of nChunk 256-wide chunks (bf16 unless fp32mask bit; optional row
// gather g0/g1). h1,h2 stay in LDS. resid is fp32 RMW; bfout optional bf16 shadow.
__global__ __launch_bounds__(256) void fused_mlp(
    const unsigned short* __restrict__ C0, const int* __restrict__ g0,
    const unsigned short* __restrict__ C1, const int* __restrict__ g1,
    const unsigned short* __restrict__ C2,
    int fp32mask, int nChunk,
    const unsigned short* __restrict__ W1, const float* __restrict__ b1,
    const unsigned short* __restrict__ W2, const float* __restrict__ b2,
    const unsigned short* __restrict__ W3, const float* __restrict__ b3,
    const float* __restrict__ lng, const float* __restrict__ lnb,
    float* __restrict__ resid, unsigned short* __restrict__ bfout, int M)
{
  __shared__ __align__(16) unsigned short As[64 * 32];    // unpadded (global_load_lds)
  __shared__ __align__(16) unsigned short Bs[256 * 32];   // unpadded (global_load_lds)
  __shared__ __align__(16) unsigned short Hs[64 * 264];   // h1/h2, +8 pad
  __shared__ float ps1[64][4];
  __shared__ float ps2[64][4];

  const int tid  = threadIdx.x;
  const int lane = tid & 63;
  const int wave = tid >> 6;
  const int lr   = lane & 15;
  const int lq   = lane >> 4;
  const int r0   = blockIdx.x * 64;

  const int ra = tid >> 2;            // 0..63: A-row / B-n-row this lane stages
  const int ka = (tid & 3) << 3;      // 8-elem k offset within 32-wide tile
  int rowA = r0 + ra;
  if (rowA > M - 1) rowA = M - 1;
  const int row0 = g0 ? g0[rowA] : rowA;
  const int row1 = g1 ? g1[rowA] : rowA;

  f32x4 acc[4][4];
  bf16x8 af[4], bq[4];

  // ---------------- Layer 1 (K = nChunk*256, A from global) ----------------
  #pragma unroll
  for (int i = 0; i < 4; i++)
    #pragma unroll
    for (int j = 0; j < 4; j++)
      acc[i][j] = (f32x4){0.f, 0.f, 0.f, 0.f};

  const int K1 = nChunk << 8;
  const int nkt1 = K1 >> 5;
  for (int kt = 0; kt < nkt1; ++kt) {
    const int chunk = kt >> 3;
    const int kloc  = (kt & 7) << 5;
    const unsigned short* base = (chunk == 0) ? C0 : (chunk == 1 ? C1 : C2);
    const int row = (chunk == 0) ? row0 : (chunk == 1 ? row1 : rowA);
    if ((fp32mask >> chunk) & 1) {
      const float* src = (const float*)base + (size_t)row * D + kloc + ka;
      float4 f0 = *(const float4*)src;
      float4 f1 = *(const float4*)(src + 4);
      uint4 p;
      p.x = f2bf(f0.x) | ((unsigned)f2bf(f0.y) << 16);
      p.y = f2bf(f0.z) | ((unsigned)f2bf(f0.w) << 16);
      p.z = f2bf(f1.x) | ((unsigned)f2bf(f1.y) << 16);
      p.w = f2bf(f1.z) | ((unsigned)f2bf(f1.w) << 16);
      *(uint4*)&As[ra * 32 + ka] = p;
    } else {
      gl_lds16(base + (size_t)row * D + kloc + ka, &As[wave * 512]);
    }
    #pragma unroll
    for (int q = 0; q < 4; ++q)
      gl_lds16(W1 + (size_t)(q * 64 + ra) * K1 + (kt << 5) + ka,
               &Bs[(q * 64 + wave * 16) * 32]);
    __syncthreads();

    #pragma unroll
    for (int mt = 0; mt < 4; ++mt)
      af[mt] = *(const bf16x8*)&As[(mt * 16 + lr) * 32 + lq * 8];
    #pragma unroll
    for (int nt = 0; nt < 4; ++nt)
      bq[nt] = *(const bf16x8*)&Bs[(wave * 64 + nt * 16 + lr) * 32 + lq * 8];
    #pragma unroll
    for (int mt = 0; mt < 4; ++mt)
      #pragma unroll
      for (int nt = 0; nt < 4; ++nt)
        acc[mt][nt] = __builtin_amdgcn_mfma_f32_16x16x32_bf16(af[mt], bq[nt], acc[mt][nt], 0, 0, 0);
    __syncthreads();
  }
  // epilogue: bias + relu -> Hs
  {
    float bv[4];
    #pragma unroll
    for (int nt = 0; nt < 4; ++nt) bv[nt] = b1[wave * 64 + nt * 16 + lr];
    #pragma unroll
    for (int mt = 0; mt < 4; ++mt)
      #pragma unroll
      for (int r = 0; r < 4; ++r) {
        const int row = mt * 16 + lq * 4 + r;
        #pragma unroll
        for (int nt = 0; nt < 4; ++nt) {
          float v = acc[mt][nt][r] + bv[nt];
          v = v > 0.f ? v : 0.f;
          Hs[row * 264 + wave * 64 + nt * 16 + lr] = f2bf(v);
        }
      }
  }

  // ---------------- Layer 2 (K = 256, A from Hs) ----------------
  #pragma unroll
  for (int i = 0; i < 4; i++)
    #pragma unroll
    for (int j = 0; j < 4; j++)
      acc[i][j] = (f32x4){0.f, 0.f, 0.f, 0.f};
  for (int kt = 0; kt < 8; ++kt) {
    #pragma unroll
    for (int q = 0; q < 4; ++q)
      gl_lds16(W2 + (size_t)(q * 64 + ra) * D + (kt << 5) + ka,
               &Bs[(q * 64 + wave * 16) * 32]);
    __syncthreads();   // also orders Hs writes (L1 epi) before Hs reads
    #pragma unroll
    for (int mt = 0; mt < 4; ++mt)
      af[mt] = *(const bf16x8*)&Hs[(mt * 16 + lr) * 264 + (kt << 5) + lq * 8];
    #pragma unroll
    for (int nt = 0; nt < 4; ++nt)
      bq[nt] = *(const bf16x8*)&Bs[(wave * 64 + nt * 16 + lr) * 32 + lq * 8];
    #pragma unroll
    for (int mt = 0; mt < 4; ++mt)
      #pragma unroll
      for (int nt = 0; nt < 4; ++nt)
        acc[mt][nt] = __builtin_amdgcn_mfma_f32_16x16x32_bf16(af[mt], bq[nt], acc[mt][nt], 0, 0, 0);
    __syncthreads();   // after this, all Hs reads of this tile set are done
  }
  {
    float bv[4];
    #pragma unroll
    for (int nt = 0; nt < 4; ++nt) bv[nt] = b2[wave * 64 + nt * 16 + lr];
    #pragma unroll
    for (int mt = 0; mt < 4; ++mt)
      #pragma unroll
      for (int r = 0; r < 4; ++r) {
        const int row = mt * 16 + lq * 4 + r;
        #pragma unroll
        for (int nt = 0; nt < 4; ++nt) {
          float v = acc[mt][nt][r] + bv[nt];
          v = v > 0.f ? v : 0.f;
          Hs[row * 264 + wave * 64 + nt * 16 + lr] = f2bf(v);
        }
      }
  }

  // ---------------- Layer 3 (K = 256, A from Hs) + LayerNorm + residual ----
  #pragma unroll
  for (int i = 0; i < 4; i++)
    #pragma unroll
    for (int j = 0; j < 4; j++)
      acc[i][j] = (f32x4){0.f, 0.f, 0.f, 0.f};
  for (int kt = 0; kt < 8; ++kt) {
    #pragma unroll
    for (int q = 0; q < 4; ++q)
      gl_lds16(W3 + (size_t)(q * 64 + ra) * D + (kt << 5) + ka,
               &Bs[(q * 64 + wave * 16) * 32]);
    __syncthreads();
    #pragma unroll
    for (int mt = 0; mt < 4; ++mt)
      af[mt] = *(const bf16x8*)&Hs[(mt * 16 + lr) * 264 + (kt << 5) + lq * 8];
    #pragma unroll
    for (int nt = 0; nt < 4; ++nt)
      bq[nt] = *(const bf16x8*)&Bs[(wave * 64 + nt * 16 + lr) * 32 + lq * 8];
    #pragma unroll
    for (int mt = 0; mt < 4; ++mt)
      #pragma unroll
      for (int nt = 0; nt < 4; ++nt)
        acc[mt][nt] = __builtin_amdgcn_mfma_f32_16x16x32_bf16(af[mt], bq[nt], acc[mt][nt], 0, 0, 0);
    __syncthreads();
  }
  // bias
  #pragma unroll
  for (int nt = 0; nt < 4; ++nt) {
    const float bv = b3[wave * 64 + nt * 16 + lr];
    #pragma unroll
    for (int mt = 0; mt < 4; ++mt)
      #pragma unroll
      for (int r = 0; r < 4; ++r)
        acc[mt][nt][r] += bv;
  }
  // LN stats
  #pragma unroll
  for (int mt = 0; mt < 4; ++mt) {
    #pragma unroll
    for (int r = 0; r < 4; ++r) {
      float s1 = 0.f, s2 = 0.f;
      #pragma unroll
      for (int nt = 0; nt < 4; ++nt) {
        float v = acc[mt][nt][r];
        s1 += v; s2 += v * v;
      }
      #pragma unroll
      for (int dlt = 1; dlt < 16; dlt <<= 1) {
        s1 += __shfl_xor(s1, dlt, 64);
        s2 += __shfl_xor(s2, dlt, 64);
      }
      if (lr == 0) {
        ps1[mt * 16 + lq * 4 + r][wave] = s1;
        ps2[mt * 16 + lq * 4 + r][wave] = s2;
      }
    }
  }
  __syncthreads();
  #pragma unroll
  for (int mt = 0; mt < 4; ++mt) {
    #pragma unroll
    for (int r = 0; r < 4; ++r) {
      const int rl = mt * 16 + lq * 4 + r;
      const int row = r0 + rl;
      float fs1 = ps1[rl][0] + ps1[rl][1] + ps1[rl][2] + ps1[rl][3];
      float fs2 = ps2[rl][0] + ps2[rl][1] + ps2[rl][2] + ps2[rl][3];
      float mean = fs1 * (1.f / 256.f);
      float var  = fs2 * (1.f / 256.f) - mean * mean;
      float rstd = rsqrtf(var + 1e-5f);
      if (row < M) {
        #pragma unroll
        for (int nt = 0; nt < 4; ++nt) {
          const int col = wave * 64 + nt * 16 + lr;
          float v = (acc[mt][nt][r] - mean) * rstd * lng[col] + lnb[col];
          float* rp = resid + (size_t)row * D + col;
          float nv = *rp + v;
          *rp = nv;
          if (bfout) bfout[(size_t)row * D + col] = f2bf(nv);
        }
      }
    }
  }
}

extern "C" void kernel_launch(void* const* d_in, const int* in_sizes, int n_in,
                              void* d_out, int out_size, void* d_ws, size_t ws_size,
                              hipStream_t stream) {
  const float* x         = (const float*)d_in[0];
  const int*   eidx      = (const int*)d_in[1];
  const float* edge_attr = (const float*)d_in[2];
  const float* eW1 = (const float*)d_in[3];
  const float* eB1 = (const float*)d_in[4];
  const float* eW2 = (const float*)d_in[5];
  const float* eB2 = (const float*)d_in[6];
  const float* eW3 = (const float*)d_in[7];
  const float* eB3 = (const float*)d_in[8];
  const float* eLNg = (const float*)d_in[9];
  const float* eLNb = (const float*)d_in[10];
  const float* nW1 = (const float*)d_in[11];
  const float* nB1 = (const float*)d_in[12];
  const float* nW2 = (const float*)d_in[13];
  const float* nB2 = (const float*)d_in[14];
  const float* nW3 = (const float*)d_in[15];
  const float* nB3 = (const float*)d_in[16];
  const float* nLNg = (const float*)d_in[17];
  const float* nLNb = (const float*)d_in[18];

  const int Nn = in_sizes[0] / D;   // 10000
  const int E  = in_sizes[1] / 2;   // 60000
  const int B  = in_sizes[4] / D;   // 9

  const int* srcI = eidx;
  const int* dstI = eidx + E;

  char* wsp = (char*)d_ws;
  size_t off = 0;
  auto alloc = [&](size_t bytes) {
    char* p = wsp + off;
    off += (bytes + 255) & ~(size_t)255;
    return p;
  };
  unsigned short* eW1t = (unsigned short*)alloc((size_t)B * 768 * D * 2);
  unsigned short* eW2t = (unsigned short*)alloc((size_t)B * 256 * D * 2);
  unsigned short* eW3t = (unsigned short*)alloc((size_t)B * 256 * D * 2);
  unsigned short* nW1t = (unsigned short*)alloc((size_t)B * 512 * D * 2);
  unsigned short* nW2t = (unsigned short*)alloc((size_t)B * 256 * D * 2);
  unsigned short* nW3t = (unsigned short*)alloc((size_t)B * 256 * D * 2);
  float*          eabuf = (float*)alloc((size_t)E * D * 4);
  unsigned short* eabf  = (unsigned short*)alloc((size_t)E * D * 2);
  unsigned short* xbf   = (unsigned short*)alloc((size_t)Nn * D * 2);
  float*          agg   = (float*)alloc((size_t)Nn * D * 4);
  int*            hist  = (int*)alloc((size_t)(Nn + 1) * 4);
  int*            offs  = (int*)alloc((size_t)(Nn + 1) * 4);
  int*            cnt   = (int*)alloc((size_t)Nn * 4);
  int*            eid   = (int*)alloc((size_t)E * 4);

  float* xbuf = (float*)d_out;  // x state lives in d_out

  auto wp = [&](const float* w, unsigned short* wt, int K) {
    int total = B * K * D;
    wprep_kernel<<<(total + 255) / 256, 256, 0, stream>>>(w, wt, K, total);
  };
  wp(eW1, eW1t, 768);
  wp(eW2, eW2t, 256);
  wp(eW3, eW3t, 256);
  wp(nW1, nW1t, 512);
  wp(nW2, nW2t, 256);
  wp(nW3, nW3t, 256);

  hipMemcpyAsync(eabuf, edge_attr, (size_t)E * D * 4, hipMemcpyDeviceToDevice, stream);
  hipMemcpyAsync(xbuf, x, (size_t)Nn * D * 4, hipMemcpyDeviceToDevice, stream);
  {
    int n4 = E * D / 4;
    cvt_bf16_kernel<<<(n4 + 255) / 256, 256, 0, stream>>>(
        (const float4*)edge_attr, (ushort4*)eabf, n4);
    int m4 = Nn * D / 4;
    cvt_bf16_kernel<<<(m4 + 255) / 256, 256, 0, stream>>>(
        (const float4*)x, (ushort4*)xbf, m4);
  }

  // CSR build (edge_index constant across blocks -> once per launch)
  hipMemsetAsync(hist, 0, (size_t)Nn * 4, stream);
  hipMemsetAsync(cnt, 0, (size_t)Nn * 4, stream);
  hist_kernel<<<(E + 255) / 256, 256, 0, stream>>>(dstI, hist, E);
  scan_kernel<<<1, 256, 0, stream>>>(hist, offs, Nn);
  fill_kernel<<<(E + 255) / 256, 256, 0, stream>>>(dstI, offs, cnt, eid, E);

  const int gridE = (E + 63) / 64;
  const int gridN = (Nn + 63) / 64;
  const int gridA = (Nn + 3) / 4;

  for (int b = 0; b < B; ++b) {
    // edge: ea += LN(MLP([x[src], x[dst], ea]))   (+ bf16 shadow eabf)
    fused_mlp<<<gridE, 256, 0, stream>>>(
        xbf, srcI, xbf, dstI, eabf, /*fp32mask*/0, /*nChunk*/3,
        eW1t + (size_t)b * 768 * D, eB1 + b * D,
        eW2t + (size_t)b * 256 * D, eB2 + b * D,
        eW3t + (size_t)b * 256 * D, eB3 + b * D,
        eLNg + b * D, eLNb + b * D, eabuf, eabf, E);
    // agg = segment_sum(ea, dst) via CSR gather
    agg_kernel<<<gridA, 256, 0, stream>>>(eabf, eid, offs, agg, Nn);
    // node: x += LN(MLP([x, agg]))   (+ bf16 shadow xbf)
    fused_mlp<<<gridN, 256, 0, stream>>>(
        xbf, nullptr, (const unsigned short*)agg, nullptr, nullptr, /*fp32mask*/2, /*nChunk*/2,
        nW1t + (size_t)b * 512 * D, nB1 + b * D,
        nW2t + (size_t)b * 256 * D, nB2 + b * D,
        nW3t + (size_t)b * 256 * D, nB3 + b * D,
        nLNg + b * D, nLNb + b * D, xbuf, xbf, Nn);
  }
}